// Round 1
// baseline (133.895 us; speedup 1.0000x reference)
//
#include <hip/hip_runtime.h>
#include <hip/hip_fp16.h>

// SuppLayer: out[b,c] = exp( sum_s x[b, cm[c,s]] * w[c,s] )
// B=4096, NCLASS=1000, NSUPP=64, NCHUNK=4096.
//
// Strategy: block handles BT=8 batch rows. Stage the 8 rows into LDS
// TRANSPOSED as fp16: slot idx = 16B = the 8 rows' values at column idx
// -> one ds_read_b128 per (class, s) gather serving 8 fp32 FMAs.
// fp16 storage halves LDS traffic; w and accumulation stay fp32.
// cm/w (512 KB) stay in L2, amortized 8x by the batch tile.

constexpr int B_       = 4096;
constexpr int NCLASS_  = 1000;
constexpr int NSUPP_   = 64;
constexpr int NCHUNK_  = 4096;
constexpr int BT       = 8;      // batch rows per block
constexpr int THREADS_ = 512;

__global__ __launch_bounds__(THREADS_, 4)
void supp_gather_kernel(const float* __restrict__ x,
                        const float* __restrict__ wSupp,
                        const int*   __restrict__ cmap,
                        float*       __restrict__ out)
{
    // tile[idx*4 + k] = half2(row 2k, row 2k+1) at column idx  (64 KB)
    __shared__ __align__(16) __half2 tile[NCHUNK_ * (BT / 2)];

    const int t  = threadIdx.x;
    const int rb = blockIdx.x * BT;   // first batch row of this tile

    // ---- stage: 8 rows of x -> fp16, transposed into LDS ----
    // each thread covers column pairs (c0, c0+1), c0 = 2t + 1024p
    for (int p = 0; p < NCHUNK_ / (2 * THREADS_); ++p) {   // 4 iterations
        const int c0 = 2 * t + 2 * THREADS_ * p;
        float2 v[BT];
        #pragma unroll
        for (int bi = 0; bi < BT; ++bi)
            v[bi] = *reinterpret_cast<const float2*>(
                        &x[(size_t)(rb + bi) * NCHUNK_ + c0]);
        __half2 h0[4], h1[4];
        #pragma unroll
        for (int k = 0; k < 4; ++k) {
            h0[k] = __floats2half2_rn(v[2 * k].x, v[2 * k + 1].x);  // col c0
            h1[k] = __floats2half2_rn(v[2 * k].y, v[2 * k + 1].y);  // col c0+1
        }
        *reinterpret_cast<float4*>(&tile[(size_t)c0 * 4]) =
            *reinterpret_cast<float4*>(h0);
        *reinterpret_cast<float4*>(&tile[(size_t)(c0 + 1) * 4]) =
            *reinterpret_cast<float4*>(h1);
    }
    __syncthreads();

    // ---- gather: one class per thread pass (2 passes: t, t+512) ----
    for (int c = t; c < NCLASS_; c += THREADS_) {
        const int4*   cm4 = reinterpret_cast<const int4*>(cmap  + c * NSUPP_);
        const float4* w4  = reinterpret_cast<const float4*>(wSupp + c * NSUPP_);
        float acc[BT] = {0.f, 0.f, 0.f, 0.f, 0.f, 0.f, 0.f, 0.f};
        #pragma unroll 2
        for (int sg = 0; sg < NSUPP_ / 4; ++sg) {
            const int4   ci = cm4[sg];
            const float4 wf = w4[sg];
            const int   idx[4] = {ci.x, ci.y, ci.z, ci.w};
            const float wv[4]  = {wf.x, wf.y, wf.z, wf.w};
            #pragma unroll
            for (int j = 0; j < 4; ++j) {
                union { float4 f4; __half2 h2[4]; } u;
                u.f4 = *reinterpret_cast<const float4*>(
                           &tile[(size_t)idx[j] * 4]);     // ds_read_b128
                #pragma unroll
                for (int k = 0; k < 4; ++k) {
                    const float2 f = __half22float2(u.h2[k]);
                    acc[2 * k]     = fmaf(f.x, wv[j], acc[2 * k]);
                    acc[2 * k + 1] = fmaf(f.y, wv[j], acc[2 * k + 1]);
                }
            }
        }
        #pragma unroll
        for (int bi = 0; bi < BT; ++bi)
            out[(size_t)(rb + bi) * NCLASS_ + c] = __expf(acc[bi]);
    }
}

extern "C" void kernel_launch(void* const* d_in, const int* in_sizes, int n_in,
                              void* d_out, int out_size, void* d_ws, size_t ws_size,
                              hipStream_t stream) {
    const float* x  = (const float*)d_in[0];   // (B, NCHUNK) fp32
    const float* w  = (const float*)d_in[1];   // (NCLASS, NSUPP) fp32
    const int*   cm = (const int*)d_in[2];     // (NCLASS, NSUPP) int32
    float*       o  = (float*)d_out;           // (B, NCLASS) fp32

    supp_gather_kernel<<<dim3(B_ / BT), dim3(THREADS_), 0, stream>>>(x, w, cm, o);
}

// Round 2
// 127.889 us; speedup vs baseline: 1.0470x; 1.0470x over previous
//
#include <hip/hip_runtime.h>
#include <hip/hip_fp16.h>

// SuppLayer: out[b,c] = exp( sum_s x[b, cm[c,s]] * w[c,s] )
// B=4096, NCLASS=1000, NSUPP=64, NCHUNK=4096.
//
// Block = 1024 threads, BT=8 batch rows, 64 KB LDS tile of x rows
// stored TRANSPOSED as fp16: tile slot idx (16 B) = the 8 rows' values at
// column idx -> one ds_read_b128 per (class,s) gather feeds 8 fp32 FMAs.
// 2 blocks/CU x 16 waves = 32 waves/CU (full occupancy) hides LDS latency.
// Staging: scalar coalesced global loads, b128 LDS writes at 16 B lane
// stride (conflict-free). One class per thread in the gather phase.

constexpr int B_       = 4096;
constexpr int NCLASS_  = 1000;
constexpr int NSUPP_   = 64;
constexpr int NCHUNK_  = 4096;
constexpr int BT       = 8;      // batch rows per block
constexpr int THREADS_ = 1024;

__global__ __launch_bounds__(THREADS_, 8)
void supp_gather_kernel(const float* __restrict__ x,
                        const float* __restrict__ wSupp,
                        const int*   __restrict__ cmap,
                        float*       __restrict__ out)
{
    // tile[c*4 + k] = half2(row 2k, row 2k+1) at column c   (64 KB)
    __shared__ __align__(16) __half2 tile[NCHUNK_ * (BT / 2)];

    const int t  = threadIdx.x;
    const int rb = blockIdx.x * BT;   // first batch row of this tile

    // ---- stage: 8 rows of x -> fp16, transposed into LDS ----
    // thread t owns columns c = t + 1024p. Global: 4B coalesced.
    // LDS write: float4 at byte addr c*16 -> lane stride 16B, conflict-free.
    #pragma unroll
    for (int p = 0; p < NCHUNK_ / THREADS_; ++p) {   // 4 iterations
        const int c = t + THREADS_ * p;
        float v[BT];
        #pragma unroll
        for (int bi = 0; bi < BT; ++bi)
            v[bi] = x[(size_t)(rb + bi) * NCHUNK_ + c];
        __half2 h[BT / 2];
        #pragma unroll
        for (int k = 0; k < BT / 2; ++k)
            h[k] = __floats2half2_rn(v[2 * k], v[2 * k + 1]);
        *reinterpret_cast<float4*>(&tile[(size_t)c * 4]) =
            *reinterpret_cast<float4*>(h);
    }
    __syncthreads();

    // ---- gather: one class per thread ----
    if (t < NCLASS_) {
        const int c = t;
        const int4*   cm4 = reinterpret_cast<const int4*>(cmap  + c * NSUPP_);
        const float4* w4  = reinterpret_cast<const float4*>(wSupp + c * NSUPP_);
        float acc[BT] = {0.f, 0.f, 0.f, 0.f, 0.f, 0.f, 0.f, 0.f};
        #pragma unroll 4
        for (int sg = 0; sg < NSUPP_ / 4; ++sg) {
            const int4   ci = cm4[sg];
            const float4 wf = w4[sg];
            const int   idx[4] = {ci.x, ci.y, ci.z, ci.w};
            const float wv[4]  = {wf.x, wf.y, wf.z, wf.w};
            #pragma unroll
            for (int j = 0; j < 4; ++j) {
                union { float4 f4; __half2 h2[4]; } u;
                u.f4 = *reinterpret_cast<const float4*>(
                           &tile[(size_t)idx[j] * 4]);     // ds_read_b128
                #pragma unroll
                for (int k = 0; k < 4; ++k) {
                    const float2 f = __half22float2(u.h2[k]);
                    acc[2 * k]     = fmaf(f.x, wv[j], acc[2 * k]);
                    acc[2 * k + 1] = fmaf(f.y, wv[j], acc[2 * k + 1]);
                }
            }
        }
        #pragma unroll
        for (int bi = 0; bi < BT; ++bi)
            out[(size_t)(rb + bi) * NCLASS_ + c] = __expf(acc[bi]);
    }
}

extern "C" void kernel_launch(void* const* d_in, const int* in_sizes, int n_in,
                              void* d_out, int out_size, void* d_ws, size_t ws_size,
                              hipStream_t stream) {
    const float* x  = (const float*)d_in[0];   // (B, NCHUNK) fp32
    const float* w  = (const float*)d_in[1];   // (NCLASS, NSUPP) fp32
    const int*   cm = (const int*)d_in[2];     // (NCLASS, NSUPP) int32
    float*       o  = (float*)d_out;           // (B, NCLASS) fp32

    supp_gather_kernel<<<dim3(B_ / BT), dim3(THREADS_), 0, stream>>>(x, w, cm, o);
}